// Round 2
// baseline (8151.360 us; speedup 1.0000x reference)
//
#include <hip/hip_runtime.h>
#include <hip/hip_bf16.h>

// GRU forward, B=64 S=512 I=512 H=1024. I/O is fp32 (reference dtypes);
// tolerance is bf16-grade (2%), so internal GEMMs run bf16 MFMA.
// Round 2: fp32 in/out; weights (and x, if ws allows) converted to bf16 in ws
// each launch; h kept fp32 with bf16 shadow. 1024 step-kernel launches.

#define B_ 64
#define S_ 512
#define I_ 512
#define H_ 1024

typedef short short8 __attribute__((ext_vector_type(8)));
typedef float floatx4 __attribute__((ext_vector_type(4)));

__device__ inline floatx4 mfma16(short8 a, short8 b, floatx4 c) {
    return __builtin_amdgcn_mfma_f32_16x16x32_bf16(a, b, c, 0, 0, 0);
}

// fp32 -> bf16 bits, round-to-nearest-even (inputs are finite)
__device__ inline short f2bf(float f) {
    union { float f; unsigned u; } v; v.f = f;
    unsigned r = (v.u + 0x7FFFu + ((v.u >> 16) & 1u)) >> 16;
    return (short)r;
}

// ---- bulk fp32 -> bf16 conversion, 8 elements/thread ----
__global__ __launch_bounds__(256) void cvt8k(const float* __restrict__ src,
                                             short* __restrict__ dst, int n8) {
    int i = blockIdx.x * 256 + threadIdx.x;
    if (i >= n8) return;
    const float4* p = reinterpret_cast<const float4*>(src) + (size_t)i * 2;
    float4 f0 = p[0], f1 = p[1];
    short8 o;
    o[0] = f2bf(f0.x); o[1] = f2bf(f0.y); o[2] = f2bf(f0.z); o[3] = f2bf(f0.w);
    o[4] = f2bf(f1.x); o[5] = f2bf(f1.y); o[6] = f2bf(f1.z); o[7] = f2bf(f1.w);
    reinterpret_cast<short8*>(dst)[i] = o;
}

// ---- init h state from h_0 (fp32 [1,B,H]) ----
__global__ __launch_bounds__(256) void gru_init(const float* __restrict__ h0,
                                                float* __restrict__ h_f32,
                                                short* __restrict__ h_bf16) {
    int i = blockIdx.x * 256 + threadIdx.x;
    if (i < B_ * H_) {
        float v = h0[i];
        h_f32[i] = v;
        h_bf16[i] = f2bf(v);
    }
}

// A-fragment from fp32 x with on-the-fly bf16 conversion
__device__ inline short8 loadA_f32(const float* p) {
    const float4* q = reinterpret_cast<const float4*>(p);
    float4 f0 = q[0], f1 = q[1];
    short8 a;
    a[0] = f2bf(f0.x); a[1] = f2bf(f0.y); a[2] = f2bf(f0.z); a[3] = f2bf(f0.w);
    a[4] = f2bf(f1.x); a[5] = f2bf(f1.y); a[6] = f2bf(f1.z); a[7] = f2bf(f1.w);
    return a;
}

// ---- P1: z = sigmoid(x_t@Wz^T + bz + h@Uz^T); rh = sigmoid(r-pre) * h ----
// grid 512 = 2 gates x 4 batch-groups x 64 row-groups, 1 wave/block.
// MFMA 16x16x32 bf16 NT: A[m=lane&15][k=quad*8+j], B-frag row n=lane&15 of W,
// D: n=lane&15, m=quad*4+reg (m89/m91-verified).
template <bool XB>
__global__ __launch_bounds__(64) void gru_zr(
    const float* __restrict__ x, const short* __restrict__ xb,
    const short* __restrict__ Wzb, const float* __restrict__ bz, const short* __restrict__ Uzb,
    const short* __restrict__ Wrb, const float* __restrict__ br, const short* __restrict__ Urb,
    const float* __restrict__ h_f32, const short* __restrict__ h_bf16,
    float* __restrict__ z_f32, short* __restrict__ rh_bf16, int t)
{
    int blk = blockIdx.x;
    int gate = blk & 1;          // 0 = z, 1 = r
    int bg   = (blk >> 1) & 3;   // batch group of 16
    int rowg = blk >> 3;         // 64 output row groups of 16
    const short* W    = gate ? Wrb : Wzb;
    const short* U    = gate ? Urb : Uzb;
    const float* bias = gate ? br : bz;

    int lane = threadIdx.x;
    int m16 = lane & 15, quad = lane >> 4;
    int bBase = bg * 16, jBase = rowg * 16;
    floatx4 acc = {0.f, 0.f, 0.f, 0.f};

    size_t xrow = ((size_t)(bBase + m16) * S_ + t) * I_;
    const short8* bw = reinterpret_cast<const short8*>(W + (size_t)(jBase + m16) * I_) + quad;
    if (XB) {
        const short8* ax = reinterpret_cast<const short8*>(xb + xrow) + quad;
#pragma unroll
        for (int it = 0; it < I_ / 32; ++it) acc = mfma16(ax[it * 4], bw[it * 4], acc);
    } else {
        const float* axf = x + xrow + quad * 8;
#pragma unroll
        for (int it = 0; it < I_ / 32; ++it)
            acc = mfma16(loadA_f32(axf + it * 32), bw[it * 4], acc);
    }

    const short8* ah = reinterpret_cast<const short8*>(h_bf16 + (size_t)(bBase + m16) * H_) + quad;
    const short8* bu = reinterpret_cast<const short8*>(U + (size_t)(jBase + m16) * H_) + quad;
#pragma unroll
    for (int it = 0; it < H_ / 32; ++it) acc = mfma16(ah[it * 4], bu[it * 4], acc);

    int j = jBase + m16;
    float bv = bias[j];
#pragma unroll
    for (int r = 0; r < 4; ++r) {
        int b = bBase + quad * 4 + r;
        float pre = acc[r] + bv;
        float g = 1.0f / (1.0f + __expf(-pre));
        size_t idx = (size_t)b * H_ + j;
        if (gate == 0) z_f32[idx] = g;
        else           rh_bf16[idx] = f2bf(g * h_f32[idx]);
    }
}

// ---- P2: h_hat = tanh(x_t@Wh^T + bh + rh@Uh^T); h = (1-z)h + z*h_hat ----
template <bool XB>
__global__ __launch_bounds__(64) void gru_h(
    const float* __restrict__ x, const short* __restrict__ xb,
    const short* __restrict__ Whb, const float* __restrict__ bh, const short* __restrict__ Uhb,
    const float* __restrict__ z_f32, const short* __restrict__ rh_bf16,
    float* __restrict__ h_f32, short* __restrict__ h_bf16,
    float* __restrict__ out, int t)
{
    int blk = blockIdx.x;
    int bg   = blk & 3;
    int rowg = blk >> 2;

    int lane = threadIdx.x;
    int m16 = lane & 15, quad = lane >> 4;
    int bBase = bg * 16, jBase = rowg * 16;
    floatx4 acc = {0.f, 0.f, 0.f, 0.f};

    size_t xrow = ((size_t)(bBase + m16) * S_ + t) * I_;
    const short8* bw = reinterpret_cast<const short8*>(Whb + (size_t)(jBase + m16) * I_) + quad;
    if (XB) {
        const short8* ax = reinterpret_cast<const short8*>(xb + xrow) + quad;
#pragma unroll
        for (int it = 0; it < I_ / 32; ++it) acc = mfma16(ax[it * 4], bw[it * 4], acc);
    } else {
        const float* axf = x + xrow + quad * 8;
#pragma unroll
        for (int it = 0; it < I_ / 32; ++it)
            acc = mfma16(loadA_f32(axf + it * 32), bw[it * 4], acc);
    }

    const short8* ar = reinterpret_cast<const short8*>(rh_bf16 + (size_t)(bBase + m16) * H_) + quad;
    const short8* bu = reinterpret_cast<const short8*>(Uhb + (size_t)(jBase + m16) * H_) + quad;
#pragma unroll
    for (int it = 0; it < H_ / 32; ++it) acc = mfma16(ar[it * 4], bu[it * 4], acc);

    int j = jBase + m16;
    float bv = bh[j];
#pragma unroll
    for (int r = 0; r < 4; ++r) {
        int b = bBase + quad * 4 + r;
        float pre = acc[r] + bv;
        float hh = tanhf(pre);
        size_t idx = (size_t)b * H_ + j;
        float z = z_f32[idx];
        float hv = h_f32[idx];
        float hn = fmaf(z, hh - hv, hv);   // (1-z)*h + z*h_hat
        h_f32[idx] = hn;
        h_bf16[idx] = f2bf(hn);
        out[(size_t)b * S_ * H_ + (size_t)t * H_ + j] = hn;
        if (t == S_ - 1) out[(size_t)B_ * S_ * H_ + idx] = hn;
    }
}

extern "C" void kernel_launch(void* const* d_in, const int* in_sizes, int n_in,
                              void* d_out, int out_size, void* d_ws, size_t ws_size,
                              hipStream_t stream) {
    const float* x  = (const float*)d_in[0];
    const float* h0 = (const float*)d_in[1];
    const float* Wz = (const float*)d_in[2];
    const float* bz = (const float*)d_in[3];
    const float* Uz = (const float*)d_in[4];
    const float* Wr = (const float*)d_in[5];
    const float* br = (const float*)d_in[6];
    const float* Ur = (const float*)d_in[7];
    const float* Wh = (const float*)d_in[8];
    const float* bh = (const float*)d_in[9];
    const float* Uh = (const float*)d_in[10];
    float* out = (float*)d_out;

    const int HB = B_ * H_;              // 65536
    const int WI = H_ * I_;              // 524288 elems per W
    const int UU = H_ * H_;              // 1048576 elems per U
    const size_t XN = (size_t)B_ * S_ * I_;  // 16777216 elems

    // ws layout: h_f32 | z_f32 | h_bf16 | rh | Wz_b Wr_b Wh_b | Uz_b Ur_b Uh_b | [x_b]
    char* w = (char*)d_ws;
    float* h_f32 = (float*)w;            w += (size_t)HB * 4;
    float* z_f32 = (float*)w;            w += (size_t)HB * 4;
    short* h_b   = (short*)w;            w += (size_t)HB * 2;
    short* rh    = (short*)w;            w += (size_t)HB * 2;
    short* Wzb   = (short*)w;            w += (size_t)WI * 2;
    short* Wrb   = (short*)w;            w += (size_t)WI * 2;
    short* Whb   = (short*)w;            w += (size_t)WI * 2;
    short* Uzb   = (short*)w;            w += (size_t)UU * 2;
    short* Urb   = (short*)w;            w += (size_t)UU * 2;
    short* Uhb   = (short*)w;            w += (size_t)UU * 2;
    size_t base_need = (size_t)(w - (char*)d_ws);
    bool XB = ws_size >= base_need + XN * 2;
    short* xb = (short*)w;

    gru_init<<<dim3(HB / 256), 256, 0, stream>>>(h0, h_f32, h_b);
    cvt8k<<<dim3(WI / 8 / 256), 256, 0, stream>>>(Wz, Wzb, WI / 8);
    cvt8k<<<dim3(WI / 8 / 256), 256, 0, stream>>>(Wr, Wrb, WI / 8);
    cvt8k<<<dim3(WI / 8 / 256), 256, 0, stream>>>(Wh, Whb, WI / 8);
    cvt8k<<<dim3(UU / 8 / 256), 256, 0, stream>>>(Uz, Uzb, UU / 8);
    cvt8k<<<dim3(UU / 8 / 256), 256, 0, stream>>>(Ur, Urb, UU / 8);
    cvt8k<<<dim3(UU / 8 / 256), 256, 0, stream>>>(Uh, Uhb, UU / 8);
    if (XB)
        cvt8k<<<dim3((int)(XN / 8 / 256)), 256, 0, stream>>>(x, xb, (int)(XN / 8));

    for (int t = 0; t < S_; ++t) {
        if (XB) {
            gru_zr<true><<<dim3(512), 64, 0, stream>>>(x, xb, Wzb, bz, Uzb, Wrb, br, Urb,
                                                       h_f32, h_b, z_f32, rh, t);
            gru_h<true><<<dim3(256), 64, 0, stream>>>(x, xb, Whb, bh, Uhb, z_f32, rh,
                                                      h_f32, h_b, out, t);
        } else {
            gru_zr<false><<<dim3(512), 64, 0, stream>>>(x, xb, Wzb, bz, Uzb, Wrb, br, Urb,
                                                        h_f32, h_b, z_f32, rh, t);
            gru_h<false><<<dim3(256), 64, 0, stream>>>(x, xb, Whb, bh, Uhb, z_f32, rh,
                                                       h_f32, h_b, out, t);
        }
    }
}